// Round 1
// 3901.574 us; speedup vs baseline: 1.0697x; 1.0697x over previous
//
#include <hip/hip_runtime.h>
#include <cstdint>
#include <cstddef>

#define B_ 128
#define P_ 196
#define ENC_ 2048
#define A_ 512
#define E_ 512
#define D_ 512
#define V_ 10000
#define L_ 52
#define T_ 51

using short8 = __attribute__((ext_vector_type(8))) short;
using short4v = __attribute__((ext_vector_type(4))) short;
using floatx4 = __attribute__((ext_vector_type(4))) float;

__device__ __forceinline__ float sigf(float x){ return 1.f/(1.f+expf(-x)); }

__device__ __forceinline__ unsigned short f2bf(float f){
  unsigned int u = __float_as_uint(f);
  unsigned int r = (u + 0x7fffu + ((u >> 16) & 1u)) >> 16;
  return (unsigned short)r;
}
__device__ __forceinline__ float bf2f(unsigned short u){
  return __uint_as_float(((unsigned int)u) << 16);
}

// ---------------- sort (stable descending by length) ----------------
__global__ void sort_kernel(const int* __restrict__ cap_len, const int* __restrict__ caps,
                            int* __restrict__ order, int* __restrict__ dec_len,
                            int* __restrict__ caps_sorted,
                            float* __restrict__ out_caps, float* __restrict__ out_declen){
  __shared__ int len_s[B_];
  int i = threadIdx.x;
  len_s[i] = cap_len[i];
  __syncthreads();
  int li = len_s[i];
  int pos = 0;
  for (int j = 0; j < B_; j++){
    int lj = len_s[j];
    pos += (lj > li) || (lj == li && j < i);
  }
  order[pos] = i;
  dec_len[pos] = li - 1;
  out_declen[pos] = (float)(li - 1);
  for (int l = 0; l < L_; l++){
    int v = caps[i * L_ + l];
    caps_sorted[pos * L_ + l] = v;
    out_caps[pos * L_ + l] = (float)v;
  }
}

// ---------------- enc gather + fp32->bf16 ----------------
// grid (392, 128), 256 thr; 392*256*4 = 401408 = P_*ENC_
__global__ void gather_kernel(const float* __restrict__ enc, const int* __restrict__ order,
                              unsigned short* __restrict__ enc_s){
  int b = blockIdx.y;
  int i = (blockIdx.x * 256 + threadIdx.x) * 4;
  const float4 v = *(const float4*)(enc + (size_t)order[b] * (P_ * ENC_) + i);
  short4v r;
  r[0] = (short)f2bf(v.x); r[1] = (short)f2bf(v.y);
  r[2] = (short)f2bf(v.z); r[3] = (short)f2bf(v.w);
  *(short4v*)(enc_s + (size_t)b * (P_ * ENC_) + i) = r;
}

// ---------------- weight conversion/packing + state init ----------------
__global__ void prep_kernel(const float* __restrict__ We, const float* __restrict__ Wd,
                            const float* __restrict__ Wbeta,
                            const float* __restrict__ W_ih, const float* __restrict__ W_hh,
                            const float* __restrict__ Wfc,
                            const float* __restrict__ bd, const float* __restrict__ bbeta,
                            const float* __restrict__ b_ih, const float* __restrict__ b_hh,
                            unsigned short* __restrict__ We_b, unsigned short* __restrict__ Wpre_b,
                            unsigned short* __restrict__ Wg_b, unsigned short* __restrict__ Wfc_b,
                            float* __restrict__ bias_pre, float* __restrict__ bias_g,
                            float* __restrict__ out_pre,
                            float* __restrict__ h, float* __restrict__ c,
                            unsigned short* __restrict__ h_b, unsigned short* __restrict__ xh){
  unsigned int idx = blockIdx.x * blockDim.x + threadIdx.x;
  unsigned int stride = gridDim.x * blockDim.x;
  // We_b: 512x2048 direct
  for (unsigned int i = idx; i < 512u * 2048u; i += stride) We_b[i] = f2bf(We[i]);
  // Wpre_b = [Wd(512x512) ; Wbeta(2048x512)] flat concat (K matches)
  for (unsigned int i = idx; i < 2560u * 512u; i += stride)
    Wpre_b[i] = f2bf(i < 512u * 512u ? Wd[i] : Wbeta[i - 512u * 512u]);
  // Wg_b rows: [W_ih row(2560) | W_hh row(512)] -> 2048 x 3072
  for (unsigned int i = idx; i < 2048u * 3072u; i += stride){
    unsigned int j = i / 3072u, k = i - j * 3072u;
    Wg_b[i] = f2bf(k < 2560u ? W_ih[j * 2560u + k] : W_hh[j * 512u + (k - 2560u)]);
  }
  // Wfc_b: 10000x512 direct
  for (unsigned int i = idx; i < 10000u * 512u; i += stride) Wfc_b[i] = f2bf(Wfc[i]);
  // biases
  for (unsigned int i = idx; i < 2560u; i += stride) bias_pre[i] = (i < 512u) ? bd[i] : bbeta[i - 512u];
  for (unsigned int i = idx; i < 2048u; i += stride) bias_g[i] = b_ih[i] + b_hh[i];
  // out_pre init (t=0) = bias broadcast
  for (unsigned int i = idx; i < (unsigned)B_ * 2560u; i += stride){
    unsigned int k = i % 2560u;
    out_pre[i] = (k < 512u) ? bd[k] : bbeta[k - 512u];
  }
  // state init
  for (unsigned int i = idx; i < (unsigned)B_ * D_; i += stride){
    h[i] = 0.f; c[i] = 0.f; h_b[i] = 0;
    unsigned int b = i >> 9, d = i & 511u;
    xh[(size_t)b * 3072 + 2560 + d] = 0;
  }
}

// ---------------- bf16 MFMA GEMM: C(MxN) = A(MxK) @ B(NxK)^T ----------------
// 128x128 block tile, 256 threads (4 waves in 2x2 of 64x64), BK=32.
// epi 0: atomicAdd fp32 into Cf (bias pre-initialized by producer) [split-K]
// epi 1: Cb[m,n] = bf16(acc + bias[n])
// epi 2: preds scatter: t=m/128,b=m%128; mask t>=dec_len[b]; Cf[(b*T+t)*V+n]
__launch_bounds__(256)
__global__ void gemm_bf16(const unsigned short* __restrict__ A, int lda,
                          const unsigned short* __restrict__ Bm, int ldb,
                          const float* __restrict__ bias,
                          float* __restrict__ Cf, unsigned short* __restrict__ Cb, int ldc,
                          int N, int ksz,
                          int epi, const int* __restrict__ dec_len)
{
  __shared__ unsigned short As[128 * 32];
  __shared__ unsigned short Bs[128 * 32];
  int tid = threadIdx.x;
  int lane = tid & 63, w = tid >> 6;
  int m0 = blockIdx.y * 128, n0 = blockIdx.x * 128;
  int kb = blockIdx.z * ksz;

  const floatx4 vzero = {0.f, 0.f, 0.f, 0.f};
  floatx4 acc[4][4];
#pragma unroll
  for (int i = 0; i < 4; i++)
#pragma unroll
    for (int j = 0; j < 4; j++) acc[i][j] = vzero;

  int mbase = (w & 1) << 6, nbase = (w >> 1) << 6;
  int fr = lane & 15, fk = (lane >> 4) << 3;

  for (int k0 = kb; k0 < kb + ksz; k0 += 32){
#pragma unroll
    for (int r = 0; r < 2; r++){
      int chunk = r * 256 + tid;
      int row = chunk >> 2, kc = (chunk & 3) << 3;
      short8 av = *(const short8*)(A + (size_t)(m0 + row) * lda + k0 + kc);
      int bn = n0 + row; if (bn >= N) bn = N - 1;
      short8 bv = *(const short8*)(Bm + (size_t)bn * ldb + k0 + kc);
      *(short8*)&As[chunk * 8] = av;
      *(short8*)&Bs[chunk * 8] = bv;
    }
    __syncthreads();
    short8 af[4], bf4[4];
#pragma unroll
    for (int i = 0; i < 4; i++){
      af[i]  = *(const short8*)&As[(mbase + i * 16 + fr) * 32 + fk];
      bf4[i] = *(const short8*)&Bs[(nbase + i * 16 + fr) * 32 + fk];
    }
#pragma unroll
    for (int mi = 0; mi < 4; mi++)
#pragma unroll
      for (int ni = 0; ni < 4; ni++)
        acc[mi][ni] = __builtin_amdgcn_mfma_f32_16x16x32_bf16(af[mi], bf4[ni], acc[mi][ni], 0, 0, 0);
    __syncthreads();
  }

#pragma unroll
  for (int mi = 0; mi < 4; mi++){
#pragma unroll
    for (int ni = 0; ni < 4; ni++){
      floatx4 v = acc[mi][ni];
      int col = n0 + nbase + ni * 16 + (lane & 15);
      int rb = m0 + mbase + mi * 16 + ((lane >> 4) << 2);
      if (epi == 0){
#pragma unroll
        for (int r = 0; r < 4; r++)
          atomicAdd(&Cf[(size_t)(rb + r) * ldc + col], v[r]);
      } else if (epi == 1){
        float bb = bias[col];
#pragma unroll
        for (int r = 0; r < 4; r++)
          Cb[(size_t)(rb + r) * ldc + col] = f2bf(v[r] + bb);
      } else {
        if (col < N){
          float bb = bias[col];
#pragma unroll
          for (int r = 0; r < 4; r++){
            int m = rb + r, t = m >> 7, b = m & 127;
            float x = (t < dec_len[b]) ? v[r] + bb : 0.f;
            Cf[((size_t)b * T_ + t) * V_ + col] = x;
          }
        }
      }
    }
  }
}

// ---------------- fused attention: scores + softmax + awe + gate + emb gather -> xh ----
// grid (2, 128) x 1024 threads (16 waves: 4 waves/SIMD for latency hiding).
// Phase 1: 16 waves compute the 196 scores (dec_att row + wf hoisted to regs).
// Phase 2: in-LDS softmax over 196.
// Phase 3: awe with 4-way p-split (49 iters/thread), LDS combine, gate, pack bf16.
// Also: init gates buffer (bias) for this step's split-K GEMM; gather emb token.
__launch_bounds__(1024)
__global__ void attn_kernel(const unsigned short* __restrict__ enc_att,
                            const unsigned short* __restrict__ enc_s,
                            const float* __restrict__ out_pre,
                            const float* __restrict__ wf, const float* __restrict__ bfp,
                            const float* __restrict__ emb, const int* __restrict__ caps_sorted,
                            unsigned short* __restrict__ xh,
                            float* __restrict__ gates, const float* __restrict__ bias_g,
                            int t){
  __shared__ float sc[P_];
  __shared__ float al[P_];
  __shared__ float red[256];
  __shared__ float4 part[4][256];
  int b = blockIdx.y, bx = blockIdx.x, tid = threadIdx.x;

  // init gates buffer for this step's split-K GEMM (previous lstm finished reading it)
  int gid = (b * 2 + bx) * 1024 + tid;   // covers exactly B_*2048
  gates[gid] = bias_g[gid & 2047];

  // ---- phase 1: scores ----
  int wid = tid >> 6, lane = tid & 63;
  float dav[8], wfv[8];
  {
    const float* dp = out_pre + (size_t)b * 2560 + lane * 8;
    *(float4*)&dav[0] = *(const float4*)(dp);
    *(float4*)&dav[4] = *(const float4*)(dp + 4);
    *(float4*)&wfv[0] = *(const float4*)(wf + lane * 8);
    *(float4*)&wfv[4] = *(const float4*)(wf + lane * 8 + 4);
  }
  float bfv = bfp[0];
  for (int p = wid; p < P_; p += 16){
    short8 e = *(const short8*)(enc_att + ((size_t)b * P_ + p) * A_ + lane * 8);
    float s = 0.f;
#pragma unroll
    for (int j = 0; j < 8; j++){
      float v = bf2f((unsigned short)e[j]) + dav[j];
      s += fmaxf(v, 0.f) * wfv[j];
    }
#pragma unroll
    for (int off = 32; off > 0; off >>= 1) s += __shfl_down(s, off);
    if (lane == 0) sc[p] = s + bfv;
  }
  __syncthreads();

  // ---- phase 2: softmax over 196 ----
  if (tid < 256) red[tid] = (tid < P_) ? sc[tid] : -1e30f;
  __syncthreads();
  for (int s = 128; s > 0; s >>= 1){ if (tid < s) red[tid] = fmaxf(red[tid], red[tid + s]); __syncthreads(); }
  float mx = red[0];
  __syncthreads();
  float ex = 0.f;
  if (tid < 256){ ex = (tid < P_) ? expf(sc[tid] - mx) : 0.f; red[tid] = ex; }
  __syncthreads();
  for (int s = 128; s > 0; s >>= 1){ if (tid < s) red[tid] += red[tid + s]; __syncthreads(); }
  float inv = 1.f / red[0];
  if (tid < P_) al[tid] = ex * inv;
  __syncthreads();

  // ---- phase 3: awe with 4-way p split ----
  int pg = tid >> 8, et = tid & 255;
  int e0 = bx * 1024 + et * 4;   // this block's 1024-wide e-slice
  const unsigned short* encb = enc_s + (size_t)b * (P_ * ENC_) + e0;
  float a0 = 0.f, a1 = 0.f, a2 = 0.f, a3 = 0.f;
  int pbeg = pg * 49;
#pragma unroll 7
  for (int p = pbeg; p < pbeg + 49; p++){
    float a = al[p];
    short4v v = *(const short4v*)(encb + (size_t)p * ENC_);
    a0 += a * bf2f((unsigned short)v[0]);
    a1 += a * bf2f((unsigned short)v[1]);
    a2 += a * bf2f((unsigned short)v[2]);
    a3 += a * bf2f((unsigned short)v[3]);
  }
  float4 pv; pv.x = a0; pv.y = a1; pv.z = a2; pv.w = a3;
  part[pg][et] = pv;
  __syncthreads();
  if (pg == 0){
    float4 s0 = part[0][et], s1 = part[1][et], s2 = part[2][et], s3 = part[3][et];
    float4 g4 = *(const float4*)(out_pre + (size_t)b * 2560 + 512 + e0);
    short4v r;
    r[0] = (short)f2bf(sigf(g4.x) * (s0.x + s1.x + s2.x + s3.x));
    r[1] = (short)f2bf(sigf(g4.y) * (s0.y + s1.y + s2.y + s3.y));
    r[2] = (short)f2bf(sigf(g4.z) * (s0.z + s1.z + s2.z + s3.z));
    r[3] = (short)f2bf(sigf(g4.w) * (s0.w + s1.w + s2.w + s3.w));
    *(short4v*)(xh + (size_t)b * 3072 + 512 + e0) = r;
  }
  // emb gather for this step's token
  if (bx == 1 && tid < 512){
    int tok = caps_sorted[b * L_ + t];
    xh[(size_t)b * 3072 + tid] = f2bf(emb[(size_t)tok * E_ + tid]);
  }
}

// ---------------- LSTM pointwise; init out_pre=bias for next step ----------------
__global__ void lstm_kernel(const float* __restrict__ gates, float* __restrict__ h, float* __restrict__ c,
                            unsigned short* __restrict__ h_b, unsigned short* __restrict__ xh,
                            unsigned short* __restrict__ hnew_b,
                            float* __restrict__ out_pre, const float* __restrict__ bias_pre,
                            const int* __restrict__ dec_len, int t){
  int idx = blockIdx.x * 256 + threadIdx.x;   // 65536 total
  int b = idx >> 9, d = idx & 511;
  const float* gr = gates + (size_t)b * 2048;
  float i_ = gr[d], f_ = gr[512 + d], g_ = gr[1024 + d], o_ = gr[1536 + d];
  float cn = sigf(f_) * c[idx] + sigf(i_) * tanhf(g_);
  float hn = sigf(o_) * tanhf(cn);
  bool act = t < dec_len[b];
  float hv = act ? hn : h[idx];
  float cv = act ? cn : c[idx];
  h[idx] = hv; c[idx] = cv;
  unsigned short hvb = f2bf(hv);
  h_b[idx] = hvb;
  xh[(size_t)b * 3072 + 2560 + d] = hvb;
  hnew_b[(size_t)t * (B_ * D_) + idx] = f2bf(hn);
  for (int j = idx; j < B_ * 2560; j += B_ * D_) out_pre[j] = bias_pre[j % 2560];
}

extern "C" void kernel_launch(void* const* d_in, const int* in_sizes, int n_in,
                              void* d_out, int out_size, void* d_ws, size_t ws_size,
                              hipStream_t stream) {
  const float* encoder_out = (const float*)d_in[0];
  const int*   caps        = (const int*)d_in[1];
  const int*   cap_len     = (const int*)d_in[2];
  const float* emb         = (const float*)d_in[3];
  const float* We          = (const float*)d_in[4];
  const float* be          = (const float*)d_in[5];
  const float* Wd          = (const float*)d_in[6];
  const float* bd          = (const float*)d_in[7];
  const float* wf          = (const float*)d_in[8];
  const float* bf          = (const float*)d_in[9];
  const float* W_ih        = (const float*)d_in[10];
  const float* b_ih        = (const float*)d_in[11];
  const float* W_hh        = (const float*)d_in[12];
  const float* b_hh        = (const float*)d_in[13];
  const float* Wbeta       = (const float*)d_in[14];
  const float* bbeta       = (const float*)d_in[15];
  const float* Wfc         = (const float*)d_in[16];
  const float* bfc         = (const float*)d_in[17];

  float* out_preds  = (float*)d_out;
  float* out_caps   = out_preds + (size_t)B_ * T_ * V_;
  float* out_declen = out_caps + (size_t)B_ * L_;

  char* w = (char*)d_ws;
  auto alloc = [&](size_t bytes) -> void* {
    void* p = (void*)w;
    w += (bytes + 255) & ~(size_t)255;
    return p;
  };
  int*   order       = (int*)alloc(B_ * 4);
  int*   dec_len     = (int*)alloc(B_ * 4);
  int*   caps_sorted = (int*)alloc((size_t)B_ * L_ * 4);
  unsigned short* enc_s   = (unsigned short*)alloc((size_t)B_ * P_ * ENC_ * 2);
  unsigned short* We_b    = (unsigned short*)alloc((size_t)512 * 2048 * 2);
  unsigned short* Wpre_b  = (unsigned short*)alloc((size_t)2560 * 512 * 2);
  unsigned short* Wg_b    = (unsigned short*)alloc((size_t)2048 * 3072 * 2);
  unsigned short* Wfc_b   = (unsigned short*)alloc((size_t)10000 * 512 * 2);
  unsigned short* enc_att = (unsigned short*)alloc((size_t)B_ * P_ * A_ * 2);
  float* bias_pre    = (float*)alloc(2560 * 4);
  float* bias_g      = (float*)alloc(2048 * 4);
  float* out_pre     = (float*)alloc((size_t)B_ * 2560 * 4);
  unsigned short* xh = (unsigned short*)alloc((size_t)B_ * 3072 * 2);
  float* gates       = (float*)alloc((size_t)B_ * 2048 * 4);
  float* h           = (float*)alloc((size_t)B_ * D_ * 4);
  float* c           = (float*)alloc((size_t)B_ * D_ * 4);
  unsigned short* h_b = (unsigned short*)alloc((size_t)B_ * D_ * 2);
  unsigned short* hnew_b = (unsigned short*)alloc((size_t)T_ * B_ * D_ * 2);

  sort_kernel<<<1, 128, 0, stream>>>(cap_len, caps, order, dec_len, caps_sorted, out_caps, out_declen);
  gather_kernel<<<dim3(392, 128), 256, 0, stream>>>(encoder_out, order, enc_s);
  prep_kernel<<<2048, 256, 0, stream>>>(We, Wd, Wbeta, W_ih, W_hh, Wfc, bd, bbeta, b_ih, b_hh,
                                        We_b, Wpre_b, Wg_b, Wfc_b, bias_pre, bias_g,
                                        out_pre, h, c, h_b, xh);

  // enc_att = enc_s @ We^T + be -> bf16 : M=25088, N=512, K=2048
  gemm_bf16<<<dim3(4, 196, 1), 256, 0, stream>>>(
      enc_s, ENC_, We_b, ENC_, be, nullptr, enc_att, A_, A_, ENC_, 1, nullptr);

  for (int t = 0; t < T_; t++){
    // out_pre += h @ [Wd;Wbeta]^T  (split-K=4, bias pre-initialized)
    gemm_bf16<<<dim3(20, 1, 4), 256, 0, stream>>>(
        h_b, D_, Wpre_b, D_, nullptr, out_pre, nullptr, 2560, 2560, 128, 0, nullptr);

    attn_kernel<<<dim3(2, B_), 1024, 0, stream>>>(enc_att, enc_s, out_pre, wf, bf,
                                                  emb, caps_sorted, xh, gates, bias_g, t);

    // gates += xh @ [W_ih|W_hh]^T  (split-K=4, bias pre-initialized by attn)
    gemm_bf16<<<dim3(16, 1, 4), 256, 0, stream>>>(
        xh, 3072, Wg_b, 3072, nullptr, gates, nullptr, 2048, 2048, 768, 0, nullptr);

    lstm_kernel<<<(B_ * D_) / 256, 256, 0, stream>>>(gates, h, c, h_b, xh, hnew_b,
                                                     out_pre, bias_pre, dec_len, t);
  }

  // preds: (T*B, V) = hnew @ Wfc^T + bfc, masked + scattered to (B,T,V)
  gemm_bf16<<<dim3(79, 51, 1), 256, 0, stream>>>(
      hnew_b, D_, Wfc_b, D_, bfc, out_preds, nullptr, 0, V_, 512, 2, dec_len);
}